// Round 15
// baseline (58.124 us; speedup 1.0000x reference)
//
#include <hip/hip_runtime.h>

#define D_IN    256
#define D_OUT   64
#define NPB     64         // nodes per bucket (bucket = row >> 6)
#define NB_MAX  800        // max buckets supported by LDS arrays
#define CAP     1280       // entries per bucket region (mean 1024, +8 sigma)
#define OVF_CAP 8192
#define GBLK    512        // threads per fused-kernel block (8 waves)
#define RPB     128        // rows per GEMM block (8 waves x 16 rows)
#define PEB     2048       // edges per partition block (392 blocks)
#define EPT     (PEB / GBLK)   // 4 edges per thread
#define GSTR    16         // gcnt stride in ints (64B: private line per bucket)

typedef __attribute__((ext_vector_type(8))) short bf16x8;
typedef __attribute__((ext_vector_type(4))) float f32x4;

static __device__ __forceinline__ unsigned f2bf(float f) {
    unsigned u = __float_as_uint(f);
    return (u + 0x7fff + ((u >> 16) & 1)) >> 16;   // RNE to bf16 (as uint)
}
static __device__ __forceinline__ float bfu(unsigned u16) {   // low 16 bits = bf16
    return __uint_as_float(u16 << 16);
}

// ---------------------------------------------------------------------------
// out[i] = b[i % 64]  (fallback path only)
__global__ void gcn_init_out(float* __restrict__ out, const float* __restrict__ b,
                             int total) {
    int i = blockIdx.x * blockDim.x + threadIdx.x;
    if (i < total) out[i] = b[i & (D_OUT - 1)];
}

// ---------------------------------------------------------------------------
// FUSED kernel.
// Blocks [0, gemm_blocks): XWb = bf16(X @ W) via MFMA 16x16x32 bf16
//   (r13-verified structure: in-loop X loads, ~96 VGPR, 2 blocks/CU).
// Blocks [gemm_blocks, ...): radix-partition 2048 edges each by bucket=row>>6.
__global__ __launch_bounds__(GBLK, 4)
void gcn_gemm_fill(const float* __restrict__ X, const float* __restrict__ W,
                   unsigned short* __restrict__ XWb,
                   const int* __restrict__ row, const int* __restrict__ col,
                   const float* __restrict__ vals,
                   uint2* __restrict__ part, int* __restrict__ gcnt,
                   int* __restrict__ ovf_cnt, int4* __restrict__ ovf,
                   int n_nodes, int n_edges, int nb, int gemm_blocks) {
    __shared__ unsigned short Wf[8 * 4 * 64 * 8];   // 32 KB (overlaid per branch)

    if ((int)blockIdx.x < gemm_blocks) {
        // ---- stage W as bf16 fragments ----
        {
            const int t = threadIdx.x;
#pragma unroll
            for (int q = 0; q < 4; ++q) {
                const int u  = q * GBLK + t;          // 0..2047 (k-pair, col4)
                const int k  = (u >> 4) * 2;
                const int c4 = (u & 15) * 4;
                const float4 w0 = *(const float4*)&W[(size_t)k * D_OUT + c4];
                const float4 w1 = *(const float4*)&W[(size_t)(k + 1) * D_OUT + c4];
#pragma unroll
                for (int cc = 0; cc < 4; ++cc) {
                    const int c = c4 + cc;
                    const unsigned pk = f2bf((&w0.x)[cc]) | (f2bf((&w1.x)[cc]) << 16);
                    const int ua = ((k >> 5) * 4 + (c >> 4)) * 512
                                 + (((k >> 3) & 3) * 16 + (c & 15)) * 8 + (k & 7);
                    *(unsigned*)&Wf[ua] = pk;
                }
            }
        }
        __syncthreads();

        const int wid   = threadIdx.x >> 6;
        const int lane  = threadIdx.x & 63;
        const int strip = blockIdx.x * 8 + wid;
        if ((size_t)strip * 16 >= (size_t)n_nodes) return;

        int arow = strip * 16 + (lane & 15);
        if (arow >= n_nodes) arow = n_nodes - 1;
        const int kh = lane >> 4;
        const float* xr = X + (size_t)arow * D_IN;

        f32x4 acc[4] = {{0,0,0,0},{0,0,0,0},{0,0,0,0},{0,0,0,0}};

        for (int kc = 0; kc < 8; ++kc) {
            const int kb = kc * 32 + kh * 8;
            const float4 a0 = *(const float4*)&xr[kb];
            const float4 a1 = *(const float4*)&xr[kb + 4];
            union { unsigned u[4]; bf16x8 v; } af;
            af.u[0] = f2bf(a0.x) | (f2bf(a0.y) << 16);
            af.u[1] = f2bf(a0.z) | (f2bf(a0.w) << 16);
            af.u[2] = f2bf(a1.x) | (f2bf(a1.y) << 16);
            af.u[3] = f2bf(a1.z) | (f2bf(a1.w) << 16);
#pragma unroll
            for (int ct = 0; ct < 4; ++ct) {
                const bf16x8 bfv = *(const bf16x8*)&Wf[((kc * 4 + ct) * 64 + lane) * 8];
                acc[ct] = __builtin_amdgcn_mfma_f32_16x16x32_bf16(af.v, bfv, acc[ct], 0, 0, 0);
            }
        }

        const int rbase = strip * 16 + (lane >> 4) * 4;
        const int cbase = lane & 15;
#pragma unroll
        for (int ct = 0; ct < 4; ++ct) {
#pragma unroll
            for (int j = 0; j < 4; ++j) {
                const int r = rbase + j;
                if (r < n_nodes)
                    XWb[(size_t)r * D_OUT + ct * 16 + cbase] =
                        (unsigned short)f2bf(acc[ct][j]);
            }
        }
    } else {
        // ---- partition branch: edges in statically-indexed registers ----
        int* hist = (int*)Wf;            // [NB_MAX]
        int* lcur = hist + NB_MAX;       // [NB_MAX] (base folded into cursor)
        const int pb = blockIdx.x - gemm_blocks;
        const int e0 = pb * PEB;
        const int e1 = (e0 + PEB < n_edges) ? e0 + PEB : n_edges;

        for (int j = threadIdx.x; j < nb; j += GBLK) hist[j] = 0;
        __syncthreads();

        int   bk[EPT];
        uint2 en[EPT];
#pragma unroll
        for (int i = 0; i < EPT; ++i) {
            const int e = e0 + i * GBLK + (int)threadIdx.x;
            if (e < e1) {
                const int   r = row[e];
                const int   c = col[e];
                const float v = vals[e];
                bk[i] = r >> 6;
                en[i] = make_uint2((unsigned)c | ((unsigned)(r & 63) << 16),
                                   __float_as_uint(v));
                atomicAdd(&hist[bk[i]], 1);
            } else {
                bk[i] = -1;
                en[i] = make_uint2(0, 0);
            }
        }
        __syncthreads();

        for (int j = threadIdx.x; j < nb; j += GBLK) {
            const int h = hist[j];
            lcur[j] = h ? atomicAdd(&gcnt[(size_t)j * GSTR], h) : 0;
        }
        __syncthreads();

#pragma unroll
        for (int i = 0; i < EPT; ++i) {
            if (bk[i] >= 0) {
                const int gp = atomicAdd(&lcur[bk[i]], 1);
                if (gp < CAP) {
                    part[(size_t)bk[i] * CAP + gp] = en[i];
                } else {
                    int op = atomicAdd(ovf_cnt, 1);
                    if (op < OVF_CAP)
                        ovf[op] = make_int4(bk[i] * NPB + (int)((en[i].x >> 16) & 0xFF),
                                            (int)(en[i].x & 0xFFFF), (int)en[i].y, 0);
                }
            }
        }
    }
}

// ---------------------------------------------------------------------------
// Reduce: block b owns nodes [b*64, b*64+64).
// LDS counting-sort by node, then register-accumulating gather:
// 8 lanes/node, lane owns 8 features; unroll-8 (8 gathers in flight).
__global__ __launch_bounds__(512, 4)
void gcn_reduce(const uint2* __restrict__ part, const int* __restrict__ gcnt,
                const unsigned short* __restrict__ XWb, const float* __restrict__ bias,
                const int* __restrict__ ovf_cnt, const int4* __restrict__ ovf,
                float* __restrict__ out, int n_nodes) {
    __shared__ uint2 raw[CAP];           // 10.24 KB
    __shared__ uint2 srt[CAP];           // 10.24 KB
    __shared__ int deg[NPB], off[NPB], cur[NPB];

    const int b  = blockIdx.x;
    const int n0 = b * NPB;
    int cnt = gcnt[(size_t)b * GSTR];
    if (cnt > CAP) cnt = CAP;

    if (threadIdx.x < NPB) deg[threadIdx.x] = 0;
    __syncthreads();

    for (int i = threadIdx.x; i < cnt; i += 512) {
        const uint2 e = part[(size_t)b * CAP + i];
        raw[i] = e;
        atomicAdd(&deg[(e.x >> 16) & 0xFF], 1);
    }
    __syncthreads();

    if (threadIdx.x < 64) {              // wave 0: inclusive scan over 64 nodes
        const int d = deg[threadIdx.x];
        int s = d;
#pragma unroll
        for (int o = 1; o < 64; o <<= 1) {
            const int t = __shfl_up(s, o);
            if ((int)threadIdx.x >= o) s += t;
        }
        off[threadIdx.x] = s - d;
        cur[threadIdx.x] = s - d;
    }
    __syncthreads();

    for (int i = threadIdx.x; i < cnt; i += 512) {
        const uint2 e = raw[i];
        const int node = (e.x >> 16) & 0xFF;
        const int p = atomicAdd(&cur[node], 1);
        srt[p] = make_uint2(e.x & 0xFFFF, e.y);
    }
    __syncthreads();

    const int node = threadIdx.x >> 3;        // 0..63
    const int fg   = (threadIdx.x & 7) * 8;   // feature base (8 bf16 = 16B)
    const int ebeg = off[node];
    const int ecnt = deg[node];

    float a0=0,a1=0,a2=0,a3=0,a4=0,a5=0,a6=0,a7=0;
    int i = 0;
    for (; i + 8 <= ecnt; i += 8) {           // 8 gathers in flight
        uint2 e[8];
        uint4 x[8];
#pragma unroll
        for (int j = 0; j < 8; ++j) e[j] = srt[ebeg + i + j];
#pragma unroll
        for (int j = 0; j < 8; ++j)
            x[j] = *(const uint4*)&XWb[(size_t)e[j].x * D_OUT + fg];
#pragma unroll
        for (int j = 0; j < 8; ++j) {
            const float v = __uint_as_float(e[j].y);
            a0 += v * bfu(x[j].x & 0xFFFF); a1 += v * bfu(x[j].x >> 16);
            a2 += v * bfu(x[j].y & 0xFFFF); a3 += v * bfu(x[j].y >> 16);
            a4 += v * bfu(x[j].z & 0xFFFF); a5 += v * bfu(x[j].z >> 16);
            a6 += v * bfu(x[j].w & 0xFFFF); a7 += v * bfu(x[j].w >> 16);
        }
    }
    for (; i < ecnt; ++i) {
        const uint2 e = srt[ebeg + i];
        const float v = __uint_as_float(e.y);
        const uint4 x = *(const uint4*)&XWb[(size_t)e.x * D_OUT + fg];
        a0 += v * bfu(x.x & 0xFFFF); a1 += v * bfu(x.x >> 16);
        a2 += v * bfu(x.y & 0xFFFF); a3 += v * bfu(x.y >> 16);
        a4 += v * bfu(x.z & 0xFFFF); a5 += v * bfu(x.z >> 16);
        a6 += v * bfu(x.w & 0xFFFF); a7 += v * bfu(x.w >> 16);
    }

    const int oc0 = *ovf_cnt;                 // overflow: expected 0
    if (oc0 > 0) {
        int oc = oc0 > OVF_CAP ? OVF_CAP : oc0;
        for (int j = 0; j < oc; ++j) {
            const int4 o = ovf[j];
            if (o.x == n0 + node) {
                const float v = __int_as_float(o.z);
                const uint4 x = *(const uint4*)&XWb[(size_t)o.y * D_OUT + fg];
                a0 += v * bfu(x.x & 0xFFFF); a1 += v * bfu(x.x >> 16);
                a2 += v * bfu(x.y & 0xFFFF); a3 += v * bfu(x.y >> 16);
                a4 += v * bfu(x.z & 0xFFFF); a5 += v * bfu(x.z >> 16);
                a6 += v * bfu(x.w & 0xFFFF); a7 += v * bfu(x.w >> 16);
            }
        }
    }

    if (n0 + node < n_nodes) {
        const float4 b0 = *(const float4*)&bias[fg];
        const float4 b1 = *(const float4*)&bias[fg + 4];
        float* op = &out[(size_t)(n0 + node) * D_OUT + fg];
        float4 o0, o1;
        o0.x = a0 + b0.x; o0.y = a1 + b0.y; o0.z = a2 + b0.z; o0.w = a3 + b0.w;
        o1.x = a4 + b1.x; o1.y = a5 + b1.y; o1.z = a6 + b1.z; o1.w = a7 + b1.w;
        *(float4*)op = o0;
        *(float4*)(op + 4) = o1;
    }
}

// ---------------------------------------------------------------------------
// Fallback: atomic scatter (used only if ws too small / nb too large)
__global__ void gcn_scatter(const int* __restrict__ row, const int* __restrict__ col,
                            const float* __restrict__ vals,
                            const unsigned short* __restrict__ XWb,
                            float* __restrict__ out, int n_edges) {
    long long t = (long long)blockIdx.x * blockDim.x + threadIdx.x;
    int e = (int)(t >> 6);
    if (e >= n_edges) return;
    int f = (int)(t & 63);
    atomicAdd(&out[(size_t)row[e] * D_OUT + f],
              vals[e] * bfu((unsigned)XWb[(size_t)col[e] * D_OUT + f]));
}

// ---------------------------------------------------------------------------
extern "C" void kernel_launch(void* const* d_in, const int* in_sizes, int n_in,
                              void* d_out, int out_size, void* d_ws, size_t ws_size,
                              hipStream_t stream) {
    const float* X    = (const float*)d_in[0];
    const int*   row  = (const int*)d_in[1];
    const int*   col  = (const int*)d_in[2];
    const float* vals = (const float*)d_in[3];
    const float* W    = (const float*)d_in[4];
    const float* b    = (const float*)d_in[5];
    float* out = (float*)d_out;

    const int n_nodes = in_sizes[0] / D_IN;
    const int n_edges = in_sizes[1];
    const int total   = n_nodes * D_OUT;
    const int nb      = (n_nodes + NPB - 1) / NPB;                  // 782

    // workspace layout (64B aligned)
    char* ws = (char*)d_ws;
    const size_t xwb_b    = (size_t)n_nodes * D_OUT * 2;            // 6.4 MB
    const size_t gcnt_off = xwb_b;
    const size_t gcnt_b   = (size_t)NB_MAX * GSTR * 4;              // 51.2 KB
    const size_t cnt_off  = gcnt_off + gcnt_b;                      // 64 B
    const size_t part_off = cnt_off + 64;
    const size_t part_b   = (size_t)nb * CAP * 8;                   // 8.0 MB
    const size_t ovf_off  = part_off + part_b;
    const size_t need     = ovf_off + (size_t)OVF_CAP * 16;         // ~14.6 MB

    unsigned short* XWb = (unsigned short*)ws;
    int*   gcnt    = (int*)(ws + gcnt_off);
    int*   ovf_cnt = (int*)(ws + cnt_off);
    uint2* part    = (uint2*)(ws + part_off);
    int4*  ovf     = (int4*)(ws + ovf_off);

    const int gemm_blocks = (n_nodes + RPB - 1) / RPB;              // 391

    if (ws_size >= need && nb <= NB_MAX) {
        hipMemsetAsync(ws + gcnt_off, 0, gcnt_b + 64, stream);
        {
            const int part_blocks = (n_edges + PEB - 1) / PEB;      // 392
            gcn_gemm_fill<<<gemm_blocks + part_blocks, GBLK, 0, stream>>>(
                X, W, XWb, row, col, vals, part, gcnt, ovf_cnt, ovf,
                n_nodes, n_edges, nb, gemm_blocks);
        }
        gcn_reduce<<<nb, 512, 0, stream>>>(
            part, gcnt, XWb, b, ovf_cnt, ovf, out, n_nodes);
    } else {
        gcn_gemm_fill<<<gemm_blocks, GBLK, 0, stream>>>(
            X, W, XWb, row, col, vals, (uint2*)(ws + xwb_b), (int*)(ws + xwb_b),
            (int*)(ws + xwb_b), (int4*)(ws + xwb_b),
            n_nodes, 0, nb, gemm_blocks);
        gcn_init_out<<<(total + 255) / 256, 256, 0, stream>>>(out, b, total);
        long long work = (long long)n_edges * 64;
        gcn_scatter<<<(int)((work + 255) / 256), 256, 0, stream>>>(
            row, col, vals, XWb, out, n_edges);
    }
}

// Round 16
// 50.250 us; speedup vs baseline: 1.1567x; 1.1567x over previous
//
#include <hip/hip_runtime.h>

#define D_IN    256
#define D_OUT   64
#define NPB     64         // nodes per bucket (bucket = row >> 6)
#define NB_MAX  800        // max buckets supported by LDS arrays
#define CAP     1280       // entries per bucket region (mean 1024, +8 sigma)
#define OVF_CAP 8192
#define GBLK    512        // threads per fused-kernel block (8 waves)
#define RPB     128        // rows per GEMM block (8 waves x 16 rows)
#define PEB     4096       // edges per partition block (196 blocks) — r13 optimum
#define EPT     (PEB / GBLK)   // 8 edges per thread
#define GSTR    16         // gcnt stride in ints (64B: private line per bucket)

typedef __attribute__((ext_vector_type(8))) short bf16x8;
typedef __attribute__((ext_vector_type(4))) float f32x4;

static __device__ __forceinline__ unsigned f2bf(float f) {
    unsigned u = __float_as_uint(f);
    return (u + 0x7fff + ((u >> 16) & 1)) >> 16;   // RNE to bf16 (as uint)
}
static __device__ __forceinline__ float bfu(unsigned u16) {   // low 16 bits = bf16
    return __uint_as_float(u16 << 16);
}

// ---------------------------------------------------------------------------
// out[i] = b[i % 64]  (fallback path only)
__global__ void gcn_init_out(float* __restrict__ out, const float* __restrict__ b,
                             int total) {
    int i = blockIdx.x * blockDim.x + threadIdx.x;
    if (i < total) out[i] = b[i & (D_OUT - 1)];
}

// ---------------------------------------------------------------------------
// FUSED kernel (r13-verified structure, PEB 4096).
// Blocks [0, gemm_blocks): XWb = bf16(X @ W) via MFMA 16x16x32 bf16.
// Blocks [gemm_blocks, ...): radix-partition 4096 edges each by bucket=row>>6.
__global__ __launch_bounds__(GBLK, 4)
void gcn_gemm_fill(const float* __restrict__ X, const float* __restrict__ W,
                   unsigned short* __restrict__ XWb,
                   const int* __restrict__ row, const int* __restrict__ col,
                   const float* __restrict__ vals,
                   uint2* __restrict__ part, int* __restrict__ gcnt,
                   int* __restrict__ ovf_cnt, int4* __restrict__ ovf,
                   int n_nodes, int n_edges, int nb, int gemm_blocks) {
    __shared__ unsigned short Wf[8 * 4 * 64 * 8];   // 32 KB (overlaid per branch)

    if ((int)blockIdx.x < gemm_blocks) {
        // ---- stage W as bf16 fragments ----
        {
            const int t = threadIdx.x;
#pragma unroll
            for (int q = 0; q < 4; ++q) {
                const int u  = q * GBLK + t;          // 0..2047 (k-pair, col4)
                const int k  = (u >> 4) * 2;
                const int c4 = (u & 15) * 4;
                const float4 w0 = *(const float4*)&W[(size_t)k * D_OUT + c4];
                const float4 w1 = *(const float4*)&W[(size_t)(k + 1) * D_OUT + c4];
#pragma unroll
                for (int cc = 0; cc < 4; ++cc) {
                    const int c = c4 + cc;
                    const unsigned pk = f2bf((&w0.x)[cc]) | (f2bf((&w1.x)[cc]) << 16);
                    const int ua = ((k >> 5) * 4 + (c >> 4)) * 512
                                 + (((k >> 3) & 3) * 16 + (c & 15)) * 8 + (k & 7);
                    *(unsigned*)&Wf[ua] = pk;
                }
            }
        }
        __syncthreads();

        const int wid   = threadIdx.x >> 6;
        const int lane  = threadIdx.x & 63;
        const int strip = blockIdx.x * 8 + wid;
        if ((size_t)strip * 16 >= (size_t)n_nodes) return;

        int arow = strip * 16 + (lane & 15);
        if (arow >= n_nodes) arow = n_nodes - 1;
        const int kh = lane >> 4;
        const float* xr = X + (size_t)arow * D_IN;

        f32x4 acc[4] = {{0,0,0,0},{0,0,0,0},{0,0,0,0},{0,0,0,0}};

        for (int kc = 0; kc < 8; ++kc) {
            const int kb = kc * 32 + kh * 8;
            const float4 a0 = *(const float4*)&xr[kb];
            const float4 a1 = *(const float4*)&xr[kb + 4];
            union { unsigned u[4]; bf16x8 v; } af;
            af.u[0] = f2bf(a0.x) | (f2bf(a0.y) << 16);
            af.u[1] = f2bf(a0.z) | (f2bf(a0.w) << 16);
            af.u[2] = f2bf(a1.x) | (f2bf(a1.y) << 16);
            af.u[3] = f2bf(a1.z) | (f2bf(a1.w) << 16);
#pragma unroll
            for (int ct = 0; ct < 4; ++ct) {
                const bf16x8 bfv = *(const bf16x8*)&Wf[((kc * 4 + ct) * 64 + lane) * 8];
                acc[ct] = __builtin_amdgcn_mfma_f32_16x16x32_bf16(af.v, bfv, acc[ct], 0, 0, 0);
            }
        }

        const int rbase = strip * 16 + (lane >> 4) * 4;
        const int cbase = lane & 15;
#pragma unroll
        for (int ct = 0; ct < 4; ++ct) {
#pragma unroll
            for (int j = 0; j < 4; ++j) {
                const int r = rbase + j;
                if (r < n_nodes)
                    XWb[(size_t)r * D_OUT + ct * 16 + cbase] =
                        (unsigned short)f2bf(acc[ct][j]);
            }
        }
    } else {
        // ---- partition branch: edges in statically-indexed registers ----
        int* hist = (int*)Wf;            // [NB_MAX]
        int* lcur = hist + NB_MAX;       // [NB_MAX] (base folded into cursor)
        const int pb = blockIdx.x - gemm_blocks;
        const int e0 = pb * PEB;
        const int e1 = (e0 + PEB < n_edges) ? e0 + PEB : n_edges;

        for (int j = threadIdx.x; j < nb; j += GBLK) hist[j] = 0;
        __syncthreads();

        int   bk[EPT];
        uint2 en[EPT];
#pragma unroll
        for (int i = 0; i < EPT; ++i) {
            const int e = e0 + i * GBLK + (int)threadIdx.x;
            if (e < e1) {
                const int   r = row[e];
                const int   c = col[e];
                const float v = vals[e];
                bk[i] = r >> 6;
                en[i] = make_uint2((unsigned)c | ((unsigned)(r & 63) << 16),
                                   __float_as_uint(v));
                atomicAdd(&hist[bk[i]], 1);
            } else {
                bk[i] = -1;
                en[i] = make_uint2(0, 0);
            }
        }
        __syncthreads();

        for (int j = threadIdx.x; j < nb; j += GBLK) {
            const int h = hist[j];
            lcur[j] = h ? atomicAdd(&gcnt[(size_t)j * GSTR], h) : 0;
        }
        __syncthreads();

#pragma unroll
        for (int i = 0; i < EPT; ++i) {
            if (bk[i] >= 0) {
                const int gp = atomicAdd(&lcur[bk[i]], 1);
                if (gp < CAP) {
                    part[(size_t)bk[i] * CAP + gp] = en[i];
                } else {
                    int op = atomicAdd(ovf_cnt, 1);
                    if (op < OVF_CAP)
                        ovf[op] = make_int4(bk[i] * NPB + (int)((en[i].x >> 16) & 0xFF),
                                            (int)(en[i].x & 0xFFFF), (int)en[i].y, 0);
                }
            }
        }
    }
}

// ---------------------------------------------------------------------------
// Reduce: block b owns nodes [b*64, b*64+64).
// LDS counting-sort by node, then register-accumulating gather:
// 8 lanes/node, lane owns 8 features; unroll-8 (8 gathers in flight).
__global__ __launch_bounds__(512, 4)
void gcn_reduce(const uint2* __restrict__ part, const int* __restrict__ gcnt,
                const unsigned short* __restrict__ XWb, const float* __restrict__ bias,
                const int* __restrict__ ovf_cnt, const int4* __restrict__ ovf,
                float* __restrict__ out, int n_nodes) {
    __shared__ uint2 raw[CAP];           // 10.24 KB
    __shared__ uint2 srt[CAP];           // 10.24 KB
    __shared__ int deg[NPB], off[NPB], cur[NPB];

    const int b  = blockIdx.x;
    const int n0 = b * NPB;
    int cnt = gcnt[(size_t)b * GSTR];
    if (cnt > CAP) cnt = CAP;

    if (threadIdx.x < NPB) deg[threadIdx.x] = 0;
    __syncthreads();

    for (int i = threadIdx.x; i < cnt; i += 512) {
        const uint2 e = part[(size_t)b * CAP + i];
        raw[i] = e;
        atomicAdd(&deg[(e.x >> 16) & 0xFF], 1);
    }
    __syncthreads();

    if (threadIdx.x < 64) {              // wave 0: inclusive scan over 64 nodes
        const int d = deg[threadIdx.x];
        int s = d;
#pragma unroll
        for (int o = 1; o < 64; o <<= 1) {
            const int t = __shfl_up(s, o);
            if ((int)threadIdx.x >= o) s += t;
        }
        off[threadIdx.x] = s - d;
        cur[threadIdx.x] = s - d;
    }
    __syncthreads();

    for (int i = threadIdx.x; i < cnt; i += 512) {
        const uint2 e = raw[i];
        const int node = (e.x >> 16) & 0xFF;
        const int p = atomicAdd(&cur[node], 1);
        srt[p] = make_uint2(e.x & 0xFFFF, e.y);
    }
    __syncthreads();

    const int node = threadIdx.x >> 3;        // 0..63
    const int fg   = (threadIdx.x & 7) * 8;   // feature base (8 bf16 = 16B)
    const int ebeg = off[node];
    const int ecnt = deg[node];

    float a0=0,a1=0,a2=0,a3=0,a4=0,a5=0,a6=0,a7=0;
    int i = 0;
    for (; i + 8 <= ecnt; i += 8) {           // 8 gathers in flight
        uint2 e[8];
        uint4 x[8];
#pragma unroll
        for (int j = 0; j < 8; ++j) e[j] = srt[ebeg + i + j];
#pragma unroll
        for (int j = 0; j < 8; ++j)
            x[j] = *(const uint4*)&XWb[(size_t)e[j].x * D_OUT + fg];
#pragma unroll
        for (int j = 0; j < 8; ++j) {
            const float v = __uint_as_float(e[j].y);
            a0 += v * bfu(x[j].x & 0xFFFF); a1 += v * bfu(x[j].x >> 16);
            a2 += v * bfu(x[j].y & 0xFFFF); a3 += v * bfu(x[j].y >> 16);
            a4 += v * bfu(x[j].z & 0xFFFF); a5 += v * bfu(x[j].z >> 16);
            a6 += v * bfu(x[j].w & 0xFFFF); a7 += v * bfu(x[j].w >> 16);
        }
    }
    for (; i < ecnt; ++i) {
        const uint2 e = srt[ebeg + i];
        const float v = __uint_as_float(e.y);
        const uint4 x = *(const uint4*)&XWb[(size_t)e.x * D_OUT + fg];
        a0 += v * bfu(x.x & 0xFFFF); a1 += v * bfu(x.x >> 16);
        a2 += v * bfu(x.y & 0xFFFF); a3 += v * bfu(x.y >> 16);
        a4 += v * bfu(x.z & 0xFFFF); a5 += v * bfu(x.z >> 16);
        a6 += v * bfu(x.w & 0xFFFF); a7 += v * bfu(x.w >> 16);
    }

    const int oc0 = *ovf_cnt;                 // overflow: expected 0
    if (oc0 > 0) {
        int oc = oc0 > OVF_CAP ? OVF_CAP : oc0;
        for (int j = 0; j < oc; ++j) {
            const int4 o = ovf[j];
            if (o.x == n0 + node) {
                const float v = __int_as_float(o.z);
                const uint4 x = *(const uint4*)&XWb[(size_t)o.y * D_OUT + fg];
                a0 += v * bfu(x.x & 0xFFFF); a1 += v * bfu(x.x >> 16);
                a2 += v * bfu(x.y & 0xFFFF); a3 += v * bfu(x.y >> 16);
                a4 += v * bfu(x.z & 0xFFFF); a5 += v * bfu(x.z >> 16);
                a6 += v * bfu(x.w & 0xFFFF); a7 += v * bfu(x.w >> 16);
            }
        }
    }

    if (n0 + node < n_nodes) {
        const float4 b0 = *(const float4*)&bias[fg];
        const float4 b1 = *(const float4*)&bias[fg + 4];
        float* op = &out[(size_t)(n0 + node) * D_OUT + fg];
        float4 o0, o1;
        o0.x = a0 + b0.x; o0.y = a1 + b0.y; o0.z = a2 + b0.z; o0.w = a3 + b0.w;
        o1.x = a4 + b1.x; o1.y = a5 + b1.y; o1.z = a6 + b1.z; o1.w = a7 + b1.w;
        *(float4*)op = o0;
        *(float4*)(op + 4) = o1;
    }
}

// ---------------------------------------------------------------------------
// Fallback: atomic scatter (used only if ws too small / nb too large)
__global__ void gcn_scatter(const int* __restrict__ row, const int* __restrict__ col,
                            const float* __restrict__ vals,
                            const unsigned short* __restrict__ XWb,
                            float* __restrict__ out, int n_edges) {
    long long t = (long long)blockIdx.x * blockDim.x + threadIdx.x;
    int e = (int)(t >> 6);
    if (e >= n_edges) return;
    int f = (int)(t & 63);
    atomicAdd(&out[(size_t)row[e] * D_OUT + f],
              vals[e] * bfu((unsigned)XWb[(size_t)col[e] * D_OUT + f]));
}

// ---------------------------------------------------------------------------
extern "C" void kernel_launch(void* const* d_in, const int* in_sizes, int n_in,
                              void* d_out, int out_size, void* d_ws, size_t ws_size,
                              hipStream_t stream) {
    const float* X    = (const float*)d_in[0];
    const int*   row  = (const int*)d_in[1];
    const int*   col  = (const int*)d_in[2];
    const float* vals = (const float*)d_in[3];
    const float* W    = (const float*)d_in[4];
    const float* b    = (const float*)d_in[5];
    float* out = (float*)d_out;

    const int n_nodes = in_sizes[0] / D_IN;
    const int n_edges = in_sizes[1];
    const int total   = n_nodes * D_OUT;
    const int nb      = (n_nodes + NPB - 1) / NPB;                  // 782

    // workspace layout (64B aligned)
    char* ws = (char*)d_ws;
    const size_t xwb_b    = (size_t)n_nodes * D_OUT * 2;            // 6.4 MB
    const size_t gcnt_off = xwb_b;
    const size_t gcnt_b   = (size_t)NB_MAX * GSTR * 4;              // 51.2 KB
    const size_t cnt_off  = gcnt_off + gcnt_b;                      // 64 B
    const size_t part_off = cnt_off + 64;
    const size_t part_b   = (size_t)nb * CAP * 8;                   // 8.0 MB
    const size_t ovf_off  = part_off + part_b;
    const size_t need     = ovf_off + (size_t)OVF_CAP * 16;         // ~14.6 MB

    unsigned short* XWb = (unsigned short*)ws;
    int*   gcnt    = (int*)(ws + gcnt_off);
    int*   ovf_cnt = (int*)(ws + cnt_off);
    uint2* part    = (uint2*)(ws + part_off);
    int4*  ovf     = (int4*)(ws + ovf_off);

    const int gemm_blocks = (n_nodes + RPB - 1) / RPB;              // 391

    if (ws_size >= need && nb <= NB_MAX) {
        hipMemsetAsync(ws + gcnt_off, 0, gcnt_b + 64, stream);
        {
            const int part_blocks = (n_edges + PEB - 1) / PEB;      // 196
            gcn_gemm_fill<<<gemm_blocks + part_blocks, GBLK, 0, stream>>>(
                X, W, XWb, row, col, vals, part, gcnt, ovf_cnt, ovf,
                n_nodes, n_edges, nb, gemm_blocks);
        }
        gcn_reduce<<<nb, 512, 0, stream>>>(
            part, gcnt, XWb, b, ovf_cnt, ovf, out, n_nodes);
    } else {
        gcn_gemm_fill<<<gemm_blocks, GBLK, 0, stream>>>(
            X, W, XWb, row, col, vals, (uint2*)(ws + xwb_b), (int*)(ws + xwb_b),
            (int*)(ws + xwb_b), (int4*)(ws + xwb_b),
            n_nodes, 0, nb, gemm_blocks);
        gcn_init_out<<<(total + 255) / 256, 256, 0, stream>>>(out, b, total);
        long long work = (long long)n_edges * 64;
        gcn_scatter<<<(int)((work + 255) / 256), 256, 0, stream>>>(
            row, col, vals, XWb, out, n_edges);
    }
}

// Round 17
// 50.153 us; speedup vs baseline: 1.1589x; 1.0019x over previous
//
#include <hip/hip_runtime.h>

#define D_IN    256
#define D_OUT   64
#define NPB     64         // nodes per bucket (bucket = row >> 6)
#define NB_MAX  800        // max buckets supported by LDS arrays (< 1024: 10-bit pack)
#define CAP     1280       // entries per bucket region (mean 1024, +8 sigma)
#define OVF_CAP 8192
#define GBLK    512        // threads per fused-kernel block (8 waves)
#define RPB     128        // rows per GEMM block (8 waves x 16 rows)
#define PEB     8192       // edges per partition block (98 blocks: halves per-line RMWs)
#define EPT     (PEB / GBLK)   // 16 edges per thread (32 VGPRs via packed en[])
#define GSTR    16         // gcnt stride in ints (64B: private line per bucket)

typedef __attribute__((ext_vector_type(8))) short bf16x8;
typedef __attribute__((ext_vector_type(4))) float f32x4;

static __device__ __forceinline__ unsigned f2bf(float f) {
    unsigned u = __float_as_uint(f);
    return (u + 0x7fff + ((u >> 16) & 1)) >> 16;   // RNE to bf16 (as uint)
}
static __device__ __forceinline__ float bfu(unsigned u16) {   // low 16 bits = bf16
    return __uint_as_float(u16 << 16);
}

// ---------------------------------------------------------------------------
// out[i] = b[i % 64]  (fallback path only)
__global__ void gcn_init_out(float* __restrict__ out, const float* __restrict__ b,
                             int total) {
    int i = blockIdx.x * blockDim.x + threadIdx.x;
    if (i < total) out[i] = b[i & (D_OUT - 1)];
}

// ---------------------------------------------------------------------------
// FUSED kernel.
// Blocks [0, gemm_blocks): XWb = bf16(X @ W) via MFMA 16x16x32 bf16 (verified).
// Blocks [gemm_blocks, ...): radix-partition 8192 edges each by bucket=row>>6.
//   Edge carried in ONE packed uint2: x = col(16b) | (row&63)<<16 | bucket<<22,
//   y = fp32 val. Sentinel: bucket 1023 (>= nb). Bucket bits masked at store.
__global__ __launch_bounds__(GBLK, 4)
void gcn_gemm_fill(const float* __restrict__ X, const float* __restrict__ W,
                   unsigned short* __restrict__ XWb,
                   const int* __restrict__ row, const int* __restrict__ col,
                   const float* __restrict__ vals,
                   uint2* __restrict__ part, int* __restrict__ gcnt,
                   int* __restrict__ ovf_cnt, int4* __restrict__ ovf,
                   int n_nodes, int n_edges, int nb, int gemm_blocks) {
    __shared__ unsigned short Wf[8 * 4 * 64 * 8];   // 32 KB (overlaid per branch)

    if ((int)blockIdx.x < gemm_blocks) {
        // ---- stage W as bf16 fragments ----
        {
            const int t = threadIdx.x;
#pragma unroll
            for (int q = 0; q < 4; ++q) {
                const int u  = q * GBLK + t;          // 0..2047 (k-pair, col4)
                const int k  = (u >> 4) * 2;
                const int c4 = (u & 15) * 4;
                const float4 w0 = *(const float4*)&W[(size_t)k * D_OUT + c4];
                const float4 w1 = *(const float4*)&W[(size_t)(k + 1) * D_OUT + c4];
#pragma unroll
                for (int cc = 0; cc < 4; ++cc) {
                    const int c = c4 + cc;
                    const unsigned pk = f2bf((&w0.x)[cc]) | (f2bf((&w1.x)[cc]) << 16);
                    const int ua = ((k >> 5) * 4 + (c >> 4)) * 512
                                 + (((k >> 3) & 3) * 16 + (c & 15)) * 8 + (k & 7);
                    *(unsigned*)&Wf[ua] = pk;
                }
            }
        }
        __syncthreads();

        const int wid   = threadIdx.x >> 6;
        const int lane  = threadIdx.x & 63;
        const int strip = blockIdx.x * 8 + wid;
        if ((size_t)strip * 16 >= (size_t)n_nodes) return;

        int arow = strip * 16 + (lane & 15);
        if (arow >= n_nodes) arow = n_nodes - 1;
        const int kh = lane >> 4;
        const float* xr = X + (size_t)arow * D_IN;

        f32x4 acc[4] = {{0,0,0,0},{0,0,0,0},{0,0,0,0},{0,0,0,0}};

        for (int kc = 0; kc < 8; ++kc) {
            const int kb = kc * 32 + kh * 8;
            const float4 a0 = *(const float4*)&xr[kb];
            const float4 a1 = *(const float4*)&xr[kb + 4];
            union { unsigned u[4]; bf16x8 v; } af;
            af.u[0] = f2bf(a0.x) | (f2bf(a0.y) << 16);
            af.u[1] = f2bf(a0.z) | (f2bf(a0.w) << 16);
            af.u[2] = f2bf(a1.x) | (f2bf(a1.y) << 16);
            af.u[3] = f2bf(a1.z) | (f2bf(a1.w) << 16);
#pragma unroll
            for (int ct = 0; ct < 4; ++ct) {
                const bf16x8 bfv = *(const bf16x8*)&Wf[((kc * 4 + ct) * 64 + lane) * 8];
                acc[ct] = __builtin_amdgcn_mfma_f32_16x16x32_bf16(af.v, bfv, acc[ct], 0, 0, 0);
            }
        }

        const int rbase = strip * 16 + (lane >> 4) * 4;
        const int cbase = lane & 15;
#pragma unroll
        for (int ct = 0; ct < 4; ++ct) {
#pragma unroll
            for (int j = 0; j < 4; ++j) {
                const int r = rbase + j;
                if (r < n_nodes)
                    XWb[(size_t)r * D_OUT + ct * 16 + cbase] =
                        (unsigned short)f2bf(acc[ct][j]);
            }
        }
    } else {
        // ---- partition branch: 16 edges/thread in packed registers ----
        int* hist = (int*)Wf;            // [NB_MAX]
        int* base = hist + NB_MAX;       // [NB_MAX]
        int* lcur = base + NB_MAX;       // [NB_MAX]
        const int pb = blockIdx.x - gemm_blocks;
        const int e0 = pb * PEB;
        const int e1 = (e0 + PEB < n_edges) ? e0 + PEB : n_edges;

        for (int j = threadIdx.x; j < nb; j += GBLK) { hist[j] = 0; lcur[j] = 0; }
        __syncthreads();

        uint2 en[EPT];
#pragma unroll
        for (int i = 0; i < EPT; ++i) {
            const int e = e0 + i * GBLK + (int)threadIdx.x;
            if (e < e1) {
                const int   r = row[e];
                const int   c = col[e];
                const float v = vals[e];
                const unsigned bkv = (unsigned)r >> 6;
                en[i] = make_uint2((unsigned)c | ((unsigned)(r & 63) << 16)
                                   | (bkv << 22), __float_as_uint(v));
                atomicAdd(&hist[bkv], 1);
            } else {
                en[i] = make_uint2(0xFFC00000u, 0);   // bucket 1023 = sentinel
            }
        }
        __syncthreads();

        for (int j = threadIdx.x; j < nb; j += GBLK) {
            const int h = hist[j];
            base[j] = h ? atomicAdd(&gcnt[(size_t)j * GSTR], h) : 0;
        }
        __syncthreads();

#pragma unroll
        for (int i = 0; i < EPT; ++i) {
            const unsigned bkv = en[i].x >> 22;
            if (bkv < (unsigned)nb) {
                const int gp = base[bkv] + atomicAdd(&lcur[bkv], 1);
                if (gp < CAP) {
                    part[(size_t)bkv * CAP + gp] =
                        make_uint2(en[i].x & 0x3FFFFFu, en[i].y);
                } else {
                    int op = atomicAdd(ovf_cnt, 1);
                    if (op < OVF_CAP)
                        ovf[op] = make_int4((int)(bkv * NPB + ((en[i].x >> 16) & 0x3F)),
                                            (int)(en[i].x & 0xFFFF), (int)en[i].y, 0);
                }
            }
        }
    }
}

// ---------------------------------------------------------------------------
// Reduce: block b owns nodes [b*64, b*64+64).
// LDS counting-sort by node, then register-accumulating gather:
// 8 lanes/node, lane owns 8 features; unroll-8 (8 gathers in flight).
__global__ __launch_bounds__(512, 4)
void gcn_reduce(const uint2* __restrict__ part, const int* __restrict__ gcnt,
                const unsigned short* __restrict__ XWb, const float* __restrict__ bias,
                const int* __restrict__ ovf_cnt, const int4* __restrict__ ovf,
                float* __restrict__ out, int n_nodes) {
    __shared__ uint2 raw[CAP];           // 10.24 KB
    __shared__ uint2 srt[CAP];           // 10.24 KB
    __shared__ int deg[NPB], off[NPB], cur[NPB];

    const int b  = blockIdx.x;
    const int n0 = b * NPB;
    int cnt = gcnt[(size_t)b * GSTR];
    if (cnt > CAP) cnt = CAP;

    if (threadIdx.x < NPB) deg[threadIdx.x] = 0;
    __syncthreads();

    for (int i = threadIdx.x; i < cnt; i += 512) {
        const uint2 e = part[(size_t)b * CAP + i];
        raw[i] = e;
        atomicAdd(&deg[(e.x >> 16) & 0xFF], 1);
    }
    __syncthreads();

    if (threadIdx.x < 64) {              // wave 0: inclusive scan over 64 nodes
        const int d = deg[threadIdx.x];
        int s = d;
#pragma unroll
        for (int o = 1; o < 64; o <<= 1) {
            const int t = __shfl_up(s, o);
            if ((int)threadIdx.x >= o) s += t;
        }
        off[threadIdx.x] = s - d;
        cur[threadIdx.x] = s - d;
    }
    __syncthreads();

    for (int i = threadIdx.x; i < cnt; i += 512) {
        const uint2 e = raw[i];
        const int node = (e.x >> 16) & 0xFF;
        const int p = atomicAdd(&cur[node], 1);
        srt[p] = make_uint2(e.x & 0xFFFF, e.y);
    }
    __syncthreads();

    const int node = threadIdx.x >> 3;        // 0..63
    const int fg   = (threadIdx.x & 7) * 8;   // feature base (8 bf16 = 16B)
    const int ebeg = off[node];
    const int ecnt = deg[node];

    float a0=0,a1=0,a2=0,a3=0,a4=0,a5=0,a6=0,a7=0;
    int i = 0;
    for (; i + 8 <= ecnt; i += 8) {           // 8 gathers in flight
        uint2 e[8];
        uint4 x[8];
#pragma unroll
        for (int j = 0; j < 8; ++j) e[j] = srt[ebeg + i + j];
#pragma unroll
        for (int j = 0; j < 8; ++j)
            x[j] = *(const uint4*)&XWb[(size_t)e[j].x * D_OUT + fg];
#pragma unroll
        for (int j = 0; j < 8; ++j) {
            const float v = __uint_as_float(e[j].y);
            a0 += v * bfu(x[j].x & 0xFFFF); a1 += v * bfu(x[j].x >> 16);
            a2 += v * bfu(x[j].y & 0xFFFF); a3 += v * bfu(x[j].y >> 16);
            a4 += v * bfu(x[j].z & 0xFFFF); a5 += v * bfu(x[j].z >> 16);
            a6 += v * bfu(x[j].w & 0xFFFF); a7 += v * bfu(x[j].w >> 16);
        }
    }
    for (; i < ecnt; ++i) {
        const uint2 e = srt[ebeg + i];
        const float v = __uint_as_float(e.y);
        const uint4 x = *(const uint4*)&XWb[(size_t)e.x * D_OUT + fg];
        a0 += v * bfu(x.x & 0xFFFF); a1 += v * bfu(x.x >> 16);
        a2 += v * bfu(x.y & 0xFFFF); a3 += v * bfu(x.y >> 16);
        a4 += v * bfu(x.z & 0xFFFF); a5 += v * bfu(x.z >> 16);
        a6 += v * bfu(x.w & 0xFFFF); a7 += v * bfu(x.w >> 16);
    }

    const int oc0 = *ovf_cnt;                 // overflow: expected 0
    if (oc0 > 0) {
        int oc = oc0 > OVF_CAP ? OVF_CAP : oc0;
        for (int j = 0; j < oc; ++j) {
            const int4 o = ovf[j];
            if (o.x == n0 + node) {
                const float v = __int_as_float(o.z);
                const uint4 x = *(const uint4*)&XWb[(size_t)o.y * D_OUT + fg];
                a0 += v * bfu(x.x & 0xFFFF); a1 += v * bfu(x.x >> 16);
                a2 += v * bfu(x.y & 0xFFFF); a3 += v * bfu(x.y >> 16);
                a4 += v * bfu(x.z & 0xFFFF); a5 += v * bfu(x.z >> 16);
                a6 += v * bfu(x.w & 0xFFFF); a7 += v * bfu(x.w >> 16);
            }
        }
    }

    if (n0 + node < n_nodes) {
        const float4 b0 = *(const float4*)&bias[fg];
        const float4 b1 = *(const float4*)&bias[fg + 4];
        float* op = &out[(size_t)(n0 + node) * D_OUT + fg];
        float4 o0, o1;
        o0.x = a0 + b0.x; o0.y = a1 + b0.y; o0.z = a2 + b0.z; o0.w = a3 + b0.w;
        o1.x = a4 + b1.x; o1.y = a5 + b1.y; o1.z = a6 + b1.z; o1.w = a7 + b1.w;
        *(float4*)op = o0;
        *(float4*)(op + 4) = o1;
    }
}

// ---------------------------------------------------------------------------
// Fallback: atomic scatter (used only if ws too small / nb too large)
__global__ void gcn_scatter(const int* __restrict__ row, const int* __restrict__ col,
                            const float* __restrict__ vals,
                            const unsigned short* __restrict__ XWb,
                            float* __restrict__ out, int n_edges) {
    long long t = (long long)blockIdx.x * blockDim.x + threadIdx.x;
    int e = (int)(t >> 6);
    if (e >= n_edges) return;
    int f = (int)(t & 63);
    atomicAdd(&out[(size_t)row[e] * D_OUT + f],
              vals[e] * bfu((unsigned)XWb[(size_t)col[e] * D_OUT + f]));
}

// ---------------------------------------------------------------------------
extern "C" void kernel_launch(void* const* d_in, const int* in_sizes, int n_in,
                              void* d_out, int out_size, void* d_ws, size_t ws_size,
                              hipStream_t stream) {
    const float* X    = (const float*)d_in[0];
    const int*   row  = (const int*)d_in[1];
    const int*   col  = (const int*)d_in[2];
    const float* vals = (const float*)d_in[3];
    const float* W    = (const float*)d_in[4];
    const float* b    = (const float*)d_in[5];
    float* out = (float*)d_out;

    const int n_nodes = in_sizes[0] / D_IN;
    const int n_edges = in_sizes[1];
    const int total   = n_nodes * D_OUT;
    const int nb      = (n_nodes + NPB - 1) / NPB;                  // 782

    // workspace layout (64B aligned)
    char* ws = (char*)d_ws;
    const size_t xwb_b    = (size_t)n_nodes * D_OUT * 2;            // 6.4 MB
    const size_t gcnt_off = xwb_b;
    const size_t gcnt_b   = (size_t)NB_MAX * GSTR * 4;              // 51.2 KB
    const size_t cnt_off  = gcnt_off + gcnt_b;                      // 64 B
    const size_t part_off = cnt_off + 64;
    const size_t part_b   = (size_t)nb * CAP * 8;                   // 8.0 MB
    const size_t ovf_off  = part_off + part_b;
    const size_t need     = ovf_off + (size_t)OVF_CAP * 16;         // ~14.6 MB

    unsigned short* XWb = (unsigned short*)ws;
    int*   gcnt    = (int*)(ws + gcnt_off);
    int*   ovf_cnt = (int*)(ws + cnt_off);
    uint2* part    = (uint2*)(ws + part_off);
    int4*  ovf     = (int4*)(ws + ovf_off);

    const int gemm_blocks = (n_nodes + RPB - 1) / RPB;              // 391

    if (ws_size >= need && nb <= NB_MAX) {
        hipMemsetAsync(ws + gcnt_off, 0, gcnt_b + 64, stream);
        {
            const int part_blocks = (n_edges + PEB - 1) / PEB;      // 98
            gcn_gemm_fill<<<gemm_blocks + part_blocks, GBLK, 0, stream>>>(
                X, W, XWb, row, col, vals, part, gcnt, ovf_cnt, ovf,
                n_nodes, n_edges, nb, gemm_blocks);
        }
        gcn_reduce<<<nb, 512, 0, stream>>>(
            part, gcnt, XWb, b, ovf_cnt, ovf, out, n_nodes);
    } else {
        gcn_gemm_fill<<<gemm_blocks, GBLK, 0, stream>>>(
            X, W, XWb, row, col, vals, (uint2*)(ws + xwb_b), (int*)(ws + xwb_b),
            (int*)(ws + xwb_b), (int4*)(ws + xwb_b),
            n_nodes, 0, nb, gemm_blocks);
        gcn_init_out<<<(total + 255) / 256, 256, 0, stream>>>(out, b, total);
        long long work = (long long)n_edges * 64;
        gcn_scatter<<<(int)((work + 255) / 256), 256, 0, stream>>>(
            row, col, vals, XWb, out, n_edges);
    }
}

// Round 18
// 45.942 us; speedup vs baseline: 1.2651x; 1.0917x over previous
//
#include <hip/hip_runtime.h>

#define D_IN    256
#define D_OUT   64
#define NPB     64         // nodes per bucket (bucket = row >> 6)
#define NB_MAX  800        // max buckets supported by LDS arrays
#define CAP     1280       // entries per bucket region (mean 1024, +8 sigma)
#define OVF_CAP 8192
#define GBLK    512        // threads per fused-kernel block (8 waves)
#define RPB     128        // rows per GEMM block (8 waves x 16 rows)
#define PEB     4096       // edges per partition block (196 blocks)

typedef __attribute__((ext_vector_type(8))) short bf16x8;
typedef __attribute__((ext_vector_type(4))) float f32x4;

static __device__ __forceinline__ unsigned f2bf(float f) {
    unsigned u = __float_as_uint(f);
    return (u + 0x7fff + ((u >> 16) & 1)) >> 16;   // RNE to bf16 (as uint)
}
static __device__ __forceinline__ float bfu(unsigned u16) {   // low 16 bits = bf16
    return __uint_as_float(u16 << 16);
}

// ---------------------------------------------------------------------------
// out[i] = b[i % 64]  (fallback path only)
__global__ void gcn_init_out(float* __restrict__ out, const float* __restrict__ b,
                             int total) {
    int i = blockIdx.x * blockDim.x + threadIdx.x;
    if (i < total) out[i] = b[i & (D_OUT - 1)];
}

// ---------------------------------------------------------------------------
// FUSED kernel (round-10 champion, 46.4 us — exact revert).
// Blocks [0, gemm_blocks): XWb = bf16(X @ W) via MFMA 16x16x32 bf16.
// Blocks [gemm_blocks, ...): radix-partition 4096 edges each by bucket=row>>6.
__global__ __launch_bounds__(GBLK, 4)
void gcn_gemm_fill(const float* __restrict__ X, const float* __restrict__ W,
                   unsigned short* __restrict__ XWb,
                   const int* __restrict__ row, const int* __restrict__ col,
                   const float* __restrict__ vals,
                   uint2* __restrict__ part, int* __restrict__ gcnt,
                   int* __restrict__ ovf_cnt, int4* __restrict__ ovf,
                   int n_nodes, int n_edges, int nb, int gemm_blocks) {
    __shared__ unsigned short Wf[8 * 4 * 64 * 8];   // 32 KB (overlaid per branch)

    if ((int)blockIdx.x < gemm_blocks) {
        // ---- stage W as bf16 fragments ----
        {
            const int t = threadIdx.x;
#pragma unroll
            for (int q = 0; q < 4; ++q) {
                const int u  = q * GBLK + t;          // 0..2047 (k-pair, col4)
                const int k  = (u >> 4) * 2;
                const int c4 = (u & 15) * 4;
                const float4 w0 = *(const float4*)&W[(size_t)k * D_OUT + c4];
                const float4 w1 = *(const float4*)&W[(size_t)(k + 1) * D_OUT + c4];
#pragma unroll
                for (int cc = 0; cc < 4; ++cc) {
                    const int c = c4 + cc;
                    const unsigned pk = f2bf((&w0.x)[cc]) | (f2bf((&w1.x)[cc]) << 16);
                    const int ua = ((k >> 5) * 4 + (c >> 4)) * 512
                                 + (((k >> 3) & 3) * 16 + (c & 15)) * 8 + (k & 7);
                    *(unsigned*)&Wf[ua] = pk;
                }
            }
        }
        __syncthreads();

        const int wid   = threadIdx.x >> 6;
        const int lane  = threadIdx.x & 63;
        const int strip = blockIdx.x * 8 + wid;
        if ((size_t)strip * 16 >= (size_t)n_nodes) return;

        int arow = strip * 16 + (lane & 15);
        if (arow >= n_nodes) arow = n_nodes - 1;
        const int kh = lane >> 4;
        const float* xr = X + (size_t)arow * D_IN;

        f32x4 acc[4] = {{0,0,0,0},{0,0,0,0},{0,0,0,0},{0,0,0,0}};

        for (int kc = 0; kc < 8; ++kc) {
            const int kb = kc * 32 + kh * 8;
            const float4 a0 = *(const float4*)&xr[kb];
            const float4 a1 = *(const float4*)&xr[kb + 4];
            union { unsigned u[4]; bf16x8 v; } af;
            af.u[0] = f2bf(a0.x) | (f2bf(a0.y) << 16);
            af.u[1] = f2bf(a0.z) | (f2bf(a0.w) << 16);
            af.u[2] = f2bf(a1.x) | (f2bf(a1.y) << 16);
            af.u[3] = f2bf(a1.z) | (f2bf(a1.w) << 16);
#pragma unroll
            for (int ct = 0; ct < 4; ++ct) {
                const bf16x8 bfv = *(const bf16x8*)&Wf[((kc * 4 + ct) * 64 + lane) * 8];
                acc[ct] = __builtin_amdgcn_mfma_f32_16x16x32_bf16(af.v, bfv, acc[ct], 0, 0, 0);
            }
        }

        // epilogue: C/D layout col=lane&15, row=(lane>>4)*4+j
        const int rbase = strip * 16 + (lane >> 4) * 4;
        const int cbase = lane & 15;
#pragma unroll
        for (int ct = 0; ct < 4; ++ct) {
#pragma unroll
            for (int j = 0; j < 4; ++j) {
                const int r = rbase + j;
                if (r < n_nodes)
                    XWb[(size_t)r * D_OUT + ct * 16 + cbase] =
                        (unsigned short)f2bf(acc[ct][j]);
            }
        }
    } else {
        // ---- partition branch ----
        int* hist = (int*)Wf;            // [NB_MAX]
        int* base = hist + NB_MAX;       // [NB_MAX]
        int* lcur = base + NB_MAX;       // [NB_MAX]
        const int pb = blockIdx.x - gemm_blocks;
        const int e0 = pb * PEB;
        const int e1 = (e0 + PEB < n_edges) ? e0 + PEB : n_edges;

        for (int j = threadIdx.x; j < nb; j += GBLK) { hist[j] = 0; lcur[j] = 0; }
        __syncthreads();
        for (int e = e0 + (int)threadIdx.x; e < e1; e += GBLK)
            atomicAdd(&hist[row[e] >> 6], 1);
        __syncthreads();
        for (int j = threadIdx.x; j < nb; j += GBLK) {
            const int h = hist[j];
            base[j] = h ? atomicAdd(&gcnt[j], h) : 0;
        }
        __syncthreads();
        for (int e = e0 + (int)threadIdx.x; e < e1; e += GBLK) {
            const int   r = row[e];
            const int   c = col[e];
            const float v = vals[e];
            const int   bk = r >> 6;
            const int   gp = base[bk] + atomicAdd(&lcur[bk], 1);
            if (gp < CAP) {
                part[(size_t)bk * CAP + gp] =
                    make_uint2((unsigned)c | ((unsigned)(r & 63) << 16),
                               __float_as_uint(v));
            } else {
                int op = atomicAdd(ovf_cnt, 1);
                if (op < OVF_CAP) ovf[op] = make_int4(r, c, __float_as_int(v), 0);
            }
        }
    }
}

// ---------------------------------------------------------------------------
// Reduce: block b owns nodes [b*64, b*64+64).
// LDS counting-sort by node, then register-accumulating gather:
// 8 lanes/node, lane owns 8 features (uint4 = 16B per edge), unroll-4.
__global__ __launch_bounds__(512, 4)
void gcn_reduce(const uint2* __restrict__ part, const int* __restrict__ gcnt,
                const unsigned short* __restrict__ XWb, const float* __restrict__ bias,
                const int* __restrict__ ovf_cnt, const int4* __restrict__ ovf,
                float* __restrict__ out, int n_nodes) {
    __shared__ uint2 raw[CAP];           // 10.24 KB
    __shared__ uint2 srt[CAP];           // 10.24 KB
    __shared__ int deg[NPB], off[NPB], cur[NPB];

    const int b  = blockIdx.x;
    const int n0 = b * NPB;
    int cnt = gcnt[b];
    if (cnt > CAP) cnt = CAP;

    if (threadIdx.x < NPB) deg[threadIdx.x] = 0;
    __syncthreads();

    for (int i = threadIdx.x; i < cnt; i += 512) {
        const uint2 e = part[(size_t)b * CAP + i];
        raw[i] = e;
        atomicAdd(&deg[(e.x >> 16) & 0xFF], 1);
    }
    __syncthreads();

    if (threadIdx.x < 64) {              // wave 0: inclusive scan over 64 nodes
        const int d = deg[threadIdx.x];
        int s = d;
#pragma unroll
        for (int o = 1; o < 64; o <<= 1) {
            const int t = __shfl_up(s, o);
            if ((int)threadIdx.x >= o) s += t;
        }
        off[threadIdx.x] = s - d;
        cur[threadIdx.x] = s - d;
    }
    __syncthreads();

    for (int i = threadIdx.x; i < cnt; i += 512) {
        const uint2 e = raw[i];
        const int node = (e.x >> 16) & 0xFF;
        const int p = atomicAdd(&cur[node], 1);
        srt[p] = make_uint2(e.x & 0xFFFF, e.y);
    }
    __syncthreads();

    const int node = threadIdx.x >> 3;        // 0..63
    const int fg   = (threadIdx.x & 7) * 8;   // feature base (8 bf16 = 16B)
    const int ebeg = off[node];
    const int ecnt = deg[node];

    float a0=0,a1=0,a2=0,a3=0,a4=0,a5=0,a6=0,a7=0;
    int i = 0;
    for (; i + 4 <= ecnt; i += 4) {           // 4 gathers in flight
        uint2 e[4];
        uint4 x[4];
#pragma unroll
        for (int j = 0; j < 4; ++j) e[j] = srt[ebeg + i + j];
#pragma unroll
        for (int j = 0; j < 4; ++j)
            x[j] = *(const uint4*)&XWb[(size_t)e[j].x * D_OUT + fg];
#pragma unroll
        for (int j = 0; j < 4; ++j) {
            const float v = __uint_as_float(e[j].y);
            a0 += v * bfu(x[j].x & 0xFFFF); a1 += v * bfu(x[j].x >> 16);
            a2 += v * bfu(x[j].y & 0xFFFF); a3 += v * bfu(x[j].y >> 16);
            a4 += v * bfu(x[j].z & 0xFFFF); a5 += v * bfu(x[j].z >> 16);
            a6 += v * bfu(x[j].w & 0xFFFF); a7 += v * bfu(x[j].w >> 16);
        }
    }
    for (; i < ecnt; ++i) {
        const uint2 e = srt[ebeg + i];
        const float v = __uint_as_float(e.y);
        const uint4 x = *(const uint4*)&XWb[(size_t)e.x * D_OUT + fg];
        a0 += v * bfu(x.x & 0xFFFF); a1 += v * bfu(x.x >> 16);
        a2 += v * bfu(x.y & 0xFFFF); a3 += v * bfu(x.y >> 16);
        a4 += v * bfu(x.z & 0xFFFF); a5 += v * bfu(x.z >> 16);
        a6 += v * bfu(x.w & 0xFFFF); a7 += v * bfu(x.w >> 16);
    }

    const int oc0 = *ovf_cnt;                 // overflow: expected 0
    if (oc0 > 0) {
        int oc = oc0 > OVF_CAP ? OVF_CAP : oc0;
        for (int j = 0; j < oc; ++j) {
            const int4 o = ovf[j];
            if (o.x == n0 + node) {
                const float v = __int_as_float(o.z);
                const uint4 x = *(const uint4*)&XWb[(size_t)o.y * D_OUT + fg];
                a0 += v * bfu(x.x & 0xFFFF); a1 += v * bfu(x.x >> 16);
                a2 += v * bfu(x.y & 0xFFFF); a3 += v * bfu(x.y >> 16);
                a4 += v * bfu(x.z & 0xFFFF); a5 += v * bfu(x.z >> 16);
                a6 += v * bfu(x.w & 0xFFFF); a7 += v * bfu(x.w >> 16);
            }
        }
    }

    if (n0 + node < n_nodes) {
        const float4 b0 = *(const float4*)&bias[fg];
        const float4 b1 = *(const float4*)&bias[fg + 4];
        float* op = &out[(size_t)(n0 + node) * D_OUT + fg];
        float4 o0, o1;
        o0.x = a0 + b0.x; o0.y = a1 + b0.y; o0.z = a2 + b0.z; o0.w = a3 + b0.w;
        o1.x = a4 + b1.x; o1.y = a5 + b1.y; o1.z = a6 + b1.z; o1.w = a7 + b1.w;
        *(float4*)op = o0;
        *(float4*)(op + 4) = o1;
    }
}

// ---------------------------------------------------------------------------
// Fallback: atomic scatter (used only if ws too small / nb too large)
__global__ void gcn_scatter(const int* __restrict__ row, const int* __restrict__ col,
                            const float* __restrict__ vals,
                            const unsigned short* __restrict__ XWb,
                            float* __restrict__ out, int n_edges) {
    long long t = (long long)blockIdx.x * blockDim.x + threadIdx.x;
    int e = (int)(t >> 6);
    if (e >= n_edges) return;
    int f = (int)(t & 63);
    atomicAdd(&out[(size_t)row[e] * D_OUT + f],
              vals[e] * bfu((unsigned)XWb[(size_t)col[e] * D_OUT + f]));
}

// ---------------------------------------------------------------------------
extern "C" void kernel_launch(void* const* d_in, const int* in_sizes, int n_in,
                              void* d_out, int out_size, void* d_ws, size_t ws_size,
                              hipStream_t stream) {
    const float* X    = (const float*)d_in[0];
    const int*   row  = (const int*)d_in[1];
    const int*   col  = (const int*)d_in[2];
    const float* vals = (const float*)d_in[3];
    const float* W    = (const float*)d_in[4];
    const float* b    = (const float*)d_in[5];
    float* out = (float*)d_out;

    const int n_nodes = in_sizes[0] / D_IN;
    const int n_edges = in_sizes[1];
    const int total   = n_nodes * D_OUT;
    const int nb      = (n_nodes + NPB - 1) / NPB;                  // 782

    // workspace layout (64B aligned)
    char* ws = (char*)d_ws;
    const size_t xwb_b    = (size_t)n_nodes * D_OUT * 2;            // 6.4 MB
    const size_t gcnt_off = xwb_b;
    const size_t gcnt_b   = (size_t)NB_MAX * 4;                     // 3.2 KB
    const size_t cnt_off  = gcnt_off + gcnt_b;                      // 64 B
    const size_t part_off = cnt_off + 64;
    const size_t part_b   = (size_t)nb * CAP * 8;                   // 8.0 MB
    const size_t ovf_off  = part_off + part_b;
    const size_t need     = ovf_off + (size_t)OVF_CAP * 16;         // ~14.6 MB

    unsigned short* XWb = (unsigned short*)ws;
    int*   gcnt    = (int*)(ws + gcnt_off);
    int*   ovf_cnt = (int*)(ws + cnt_off);
    uint2* part    = (uint2*)(ws + part_off);
    int4*  ovf     = (int4*)(ws + ovf_off);

    const int gemm_blocks = (n_nodes + RPB - 1) / RPB;              // 391

    if (ws_size >= need && nb <= NB_MAX) {
        // zero gcnt + ovf_cnt (contiguous)
        hipMemsetAsync(ws + gcnt_off, 0, gcnt_b + 64, stream);
        // fused GEMM + radix partition
        {
            const int part_blocks = (n_edges + PEB - 1) / PEB;      // 196
            gcn_gemm_fill<<<gemm_blocks + part_blocks, GBLK, 0, stream>>>(
                X, W, XWb, row, col, vals, part, gcnt, ovf_cnt, ovf,
                n_nodes, n_edges, nb, gemm_blocks);
        }
        // per-bucket LDS reduce -> out (full overwrite)
        gcn_reduce<<<nb, 512, 0, stream>>>(
            part, gcnt, XWb, b, ovf_cnt, ovf, out, n_nodes);
    } else {
        gcn_gemm_fill<<<gemm_blocks, GBLK, 0, stream>>>(
            X, W, XWb, row, col, vals, (uint2*)(ws + xwb_b), (int*)(ws + xwb_b),
            (int*)(ws + xwb_b), (int4*)(ws + xwb_b),
            n_nodes, 0, nb, gemm_blocks);
        gcn_init_out<<<(total + 255) / 256, 256, 0, stream>>>(out, b, total);
        long long work = (long long)n_edges * 64;
        gcn_scatter<<<(int)((work + 255) / 256), 256, 0, stream>>>(
            row, col, vals, XWb, out, n_edges);
    }
}